// Round 8
// baseline (304.994 us; speedup 1.0000x reference)
//
#include <hip/hip_runtime.h>
#include <hip/hip_bf16.h>
#include <stdint.h>

// Problem constants (fixed by the reference).
#define T_DIM 8192
#define S_DIM 1024
#define B_DIM 8192
#define CHUNK 32
#define NCHUNK 256     // = grid size; 256 blocks x 16 waves <= capacity -> co-resident
#define SUPER 16       // chunks per super-chunk
#define NSUPER 16
#define QCAP 1024      // per-chunk query cap; E=32, >100 sigma margin

// Workspace layout (5.31 MB; ws_size >= 9.44 MB proven in R4/R6)
#define OFF_ALPHAT 0u          // 4 MB   f32 [S][S]   alphaT[s][sp]
#define OFF_W      4194304u    // 1 MB   f32 [NCHUNK][S]
#define OFF_SW     5242880u    // 64 KB  f32 [NSUPER][S]
#define OFF_CNT    5308416u    // 128 B  two barrier counters (memset 0 on stream)
#define WS_NEEDED  5308544u

// Grid barrier: release(fence+agent add) / acquire(spin+fence). Proven in R6.
__device__ __forceinline__ void grid_barrier(int* cnt) {
    __syncthreads();
    if (threadIdx.x == 0) {
        __threadfence();
        __hip_atomic_fetch_add(cnt, 1, __ATOMIC_RELEASE, __HIP_MEMORY_SCOPE_AGENT);
        int spins = 0;
        while (__hip_atomic_load(cnt, __ATOMIC_ACQUIRE, __HIP_MEMORY_SCOPE_AGENT)
               < NCHUNK) {
            __builtin_amdgcn_s_sleep(2);
            if (++spins > 8000000) break;   // loud-failure safety valve
        }
    }
    __syncthreads();
    __threadfence();
}

// ---------------------------------------------------------------------------
// Single dispatch, 4 phases / 2 grid barriers. Block b == chunk k, 1024 thr,
// thread tid owns column sp = tid.
//  P0: bucket+j-sort chunk queries (LDS); transpose 4 alpha cols; W[k] =
//      ascending 32-row Horner fold (W[k] = sum_r a^(32-r) obs[t0+r]).
//  B1. P1: blocks 0..15: SW[m] = sum_c Z^(15-c) W[16m+c],  Z = a^32.
//  B2. P2: U_k = Z^c * SU[m] + sum_{c'<c} Z^(c-1-c') W[16m+c'],  k = 16m+c,
//      SU[m] = prefix of SW (<=15 terms, recomputed per block).
//  P3: roll G through 32 rows; at offset j answer queries with t == t0+j via
//      coalesced dot with alphaT row (16-wave fan-out over j-sorted list).
__global__ __launch_bounds__(1024) void hawkes_fused_kernel(
        const int* __restrict__ tq, const int* __restrict__ sq,
        const int* __restrict__ obs,      // [T][S] int32
        const float* __restrict__ alpha,  // [S][S] f32, alpha[sp][s]
        const float* __restrict__ beta, const float* __restrict__ mu,
        float* __restrict__ alphaT, float* __restrict__ W,
        float* __restrict__ SW, int* __restrict__ cnt,
        float* __restrict__ out) {
    const int k   = blockIdx.x;
    const int tid = threadIdx.x;
    const int wv  = tid >> 6, lane = tid & 63;
    const float b = beta[0];
    const float a = expf(-b);
    const int t0 = k << 5;

    __shared__ int   qtmp[QCAP];
    __shared__ int   qkey[QCAP];          // j-sorted; (j<<13)|i
    __shared__ int   jcnt[CHUNK];
    __shared__ int   jstart[CHUNK + 1];
    __shared__ int   qcnt_s;
    __shared__ float Gs[S_DIM];

    if (tid == 0) qcnt_s = 0;
    if (tid < CHUNK) jcnt[tid] = 0;
    __syncthreads();

    // ---- P0a: bucket this chunk's queries ----
    for (int i = tid; i < B_DIM; i += 1024) {
        int tv = tq[i];
        if ((tv >> 5) == k) {
            int p = atomicAdd(&qcnt_s, 1);
            if (p < QCAP) {
                qtmp[p] = ((tv - t0) << 13) | i;
                atomicAdd(&jcnt[tv - t0], 1);
            }
        }
    }
    __syncthreads();
    int Q = qcnt_s < QCAP ? qcnt_s : QCAP;
    if (tid == 0) {
        int acc = 0;
        for (int j = 0; j < CHUNK; ++j) { jstart[j] = acc; acc += jcnt[j]; }
        jstart[CHUNK] = acc;
    }
    __syncthreads();
    if (tid < CHUNK) jcnt[tid] = 0;       // reuse as scatter cursors
    __syncthreads();
    for (int p = tid; p < Q; p += 1024) {
        int key = qtmp[p], j = key >> 13;
        qkey[jstart[j] + atomicAdd(&jcnt[j], 1)] = key;
    }   // visibility covered by barrier B1's __syncthreads

    // ---- P0b: alphaT rows [4k, 4k+4) ----
    #pragma unroll
    for (int c = 0; c < 4; ++c) {
        int srow = 4 * k + c;
        alphaT[(size_t)srow * S_DIM + tid] = alpha[(size_t)tid * S_DIM + srow];
    }

    // ---- P0c: W[k] fold, ASCENDING (o[t0+31] weight a^1, o[t0] weight a^32)
    float acc = 0.f;
    for (int base = 0; base < CHUNK; base += 8) {
        int o[8];
        #pragma unroll
        for (int r = 0; r < 8; ++r)
            o[r] = obs[(size_t)(t0 + base + r) * S_DIM + tid];
        #pragma unroll
        for (int r = 0; r < 8; ++r)
            acc = a * (acc + (float)o[r]);
    }
    W[(size_t)k * S_DIM + tid] = acc;

    grid_barrier(cnt);                     // B1

    // ---- P1: super-sums (blocks 0..15), ascending fold with factor Z ----
    float Z = a;
    #pragma unroll
    for (int q = 0; q < 5; ++q) Z *= Z;    // a^32
    if (k < NSUPER) {
        float sacc = 0.f;
        #pragma unroll 4
        for (int c = 0; c < SUPER; ++c)
            sacc = Z * sacc + W[(size_t)(SUPER * k + c) * S_DIM + tid];
        SW[(size_t)k * S_DIM + tid] = sacc;
    }

    grid_barrier(cnt + 16);                // B2

    // ---- P2: start state U_k ----
    float Z16 = Z;
    #pragma unroll
    for (int q = 0; q < 4; ++q) Z16 *= Z16;  // a^512
    const int m = k >> 4, c = k & 15;
    float G = 0.f;
    for (int mp = 0; mp < m; ++mp)         // SU[m]
        G = Z16 * G + SW[(size_t)mp * S_DIM + tid];
    for (int cp = 0; cp < c; ++cp)         // + chunk steps within super
        G = Z * G + W[(size_t)(SUPER * m + cp) * S_DIM + tid];

    // ---- P3: roll 32 rows, answering queries ----
    for (int j = 0; j < CHUNK; ++j) {
        Gs[tid] = G;
        int onext = obs[(size_t)(t0 + j) * S_DIM + tid];  // issued pre-barrier
        __syncthreads();                   // Gs (+ first-iter qkey) visible
        for (int q = jstart[j] + wv; q < jstart[j + 1]; q += 16) {
            int i = qkey[q] & 8191;
            int s = sq[i];
            const float* ar = alphaT + (size_t)s * S_DIM;
            float p = 0.f;
            #pragma unroll
            for (int cc = 0; cc < 16; ++cc) {
                int col = lane + 64 * cc;  // LDS 2-way (free), global coalesced
                p += Gs[col] * ar[col];
            }
            #pragma unroll
            for (int off = 32; off > 0; off >>= 1)
                p += __shfl_down(p, off);
            if (lane == 0) {
                float lam = mu[s] + b * p;
                out[i] = lam > 0.f ? lam : 0.f;
            }
        }
        __syncthreads();                   // queries done before Gs overwrite
        G = a * (G + (float)onext);        // absorb row t0+j
    }
}

// ---------------------------------------------------------------------------
// Fallback: proven R5 single-kernel zero-ws version (874 us, absmax 0.0).
__global__ __launch_bounds__(1024) void chunk_all_kernel(
        const int* __restrict__ tq, const int* __restrict__ sq,
        const int* __restrict__ obs, const float* __restrict__ alpha,
        const float* __restrict__ beta, const float* __restrict__ mu,
        float* __restrict__ out) {
    const int k   = blockIdx.x;
    const int tid = threadIdx.x;
    const float b = beta[0];
    const float a = expf(-b);
    const int t0 = k << 6;
    __shared__ int   qkey[2048];
    __shared__ int   qcnt_s;
    __shared__ float wred[16];
    if (tid == 0) qcnt_s = 0;
    __syncthreads();
    for (int i = tid; i < B_DIM; i += 1024) {
        int tv = tq[i];
        if ((tv >> 6) == k) {
            int p = atomicAdd(&qcnt_s, 1);
            if (p < 2048) qkey[p] = ((tv - t0) << 13) | i;
        }
    }
    __syncthreads();
    int Q = qcnt_s; if (Q > 2048) Q = 2048;
    float G = 0.f;
    for (int tp = 0; tp < t0; tp += 8) {
        int o[8];
        #pragma unroll
        for (int r = 0; r < 8; ++r) o[r] = obs[(size_t)(tp + r) * S_DIM + tid];
        #pragma unroll
        for (int r = 0; r < 8; ++r) G = a * (G + (float)o[r]);
    }
    for (int j = 0; j < 64; ++j) {
        for (int q = 0; q < Q; ++q) {
            int key = qkey[q];
            if ((key >> 13) == j) {
                int i = key & 8191;
                int s = sq[i];
                float p = G * alpha[(size_t)tid * S_DIM + s];
                #pragma unroll
                for (int off = 32; off > 0; off >>= 1) p += __shfl_down(p, off);
                if ((tid & 63) == 0) wred[tid >> 6] = p;
                __syncthreads();
                if (tid < 64) {
                    float v = (tid < 16) ? wred[tid] : 0.f;
                    v += __shfl_down(v, 8); v += __shfl_down(v, 4);
                    v += __shfl_down(v, 2); v += __shfl_down(v, 1);
                    if (tid == 0) {
                        float lam = mu[s] + b * v;
                        out[i] = lam > 0.f ? lam : 0.f;
                    }
                }
                __syncthreads();
            }
        }
        int o = obs[(size_t)(t0 + j) * S_DIM + tid];
        G = a * (G + (float)o);
    }
}

// ---------------------------------------------------------------------------
extern "C" void kernel_launch(void* const* d_in, const int* in_sizes, int n_in,
                              void* d_out, int out_size, void* d_ws, size_t ws_size,
                              hipStream_t stream) {
    const int*   t     = (const int*)d_in[0];
    const int*   s     = (const int*)d_in[1];
    const int*   obs   = (const int*)d_in[2];
    const float* alpha = (const float*)d_in[3];
    const float* beta  = (const float*)d_in[4];
    const float* mu    = (const float*)d_in[5];
    float* out = (float*)d_out;

    if (ws_size < (size_t)WS_NEEDED || d_ws == nullptr) {
        chunk_all_kernel<<<128, 1024, 0, stream>>>(t, s, obs, alpha, beta, mu, out);
        return;
    }

    char* ws = (char*)d_ws;
    float* alphaT = (float*)(ws + OFF_ALPHAT);
    float* W      = (float*)(ws + OFF_W);
    float* SW     = (float*)(ws + OFF_SW);
    int*   cnt    = (int*)  (ws + OFF_CNT);

    hipMemsetAsync(cnt, 0, 128, stream);   // both barrier counters
    hawkes_fused_kernel<<<NCHUNK, 1024, 0, stream>>>(
        t, s, obs, alpha, beta, mu, alphaT, W, SW, cnt, out);
}

// Round 9
// 114.874 us; speedup vs baseline: 2.6550x; 2.6550x over previous
//
#include <hip/hip_runtime.h>
#include <hip/hip_bf16.h>
#include <stdint.h>

// Problem constants (fixed by the reference).
#define T_DIM 8192
#define S_DIM 1024
#define B_DIM 8192
#define CHUNK 32
#define NCHUNK 256      // one block per chunk; 256 blocks = 1 per CU
#define QCAP 2048       // per-chunk query cap; E=32, absurd margin
#define PASS_ROWS 8
#define NPASS 4         // 4 passes x 8 rows = 32-row chunk roll

// Workspace: only alphaT (4 MB). ws_size >= 9.44 MB proven in R4/R6.
#define WS_NEEDED 4194304u

// ---------------------------------------------------------------------------
// K1: alphaT[s][sp] = alpha[sp][s]  (f32, coalesced tiled transpose)
__global__ void transpose_alpha_kernel(const float* __restrict__ alpha,
                                       float* __restrict__ alphaT) {
    __shared__ float tile[32][33];
    int bx = blockIdx.x * 32;  // s base
    int by = blockIdx.y * 32;  // sp base
    int tx = threadIdx.x, ty = threadIdx.y;  // 32 x 8
    #pragma unroll
    for (int j = 0; j < 32; j += 8)
        tile[ty + j][tx] = alpha[(size_t)(by + ty + j) * S_DIM + bx + tx];
    __syncthreads();
    #pragma unroll
    for (int j = 0; j < 32; j += 8)
        alphaT[(size_t)(bx + ty + j) * S_DIM + by + tx] = tile[tx][ty + j];
}

// ---------------------------------------------------------------------------
// K2: fully self-contained per-chunk kernel (NO grid barrier).
// Truncated window: events older than n steps, with beta*n >= 26, contribute
// < 4e-8 to lambda (a^n/(1-a) * c_max * beta with c_max<=4096) -> below f32
// resolution. n computed from beta at runtime; capped at t0 (always exact
// for early chunks).
//  1) bucket this chunk's queries into LDS (unsorted),
//  2) prefix U[sp] = sum_{tp in [t0-n, t0)} a^(t0-tp) obs[tp][sp] via
//     4-phase decimated Horner with int4 loads:
//       w = 4q+m: U = sum_m a^{-m} F_m,  F_m = sum_q (a^4)^(Q-q) o_{4q+m}
//     (ascending folds; weight check: (a^4)^(Q-q)*a^{-m} = a^{n-4q-m} ✓),
//  3) roll 32 rows in 4 passes of 8, caching states Gall[j][sp] in LDS;
//     after each pass all 16 waves answer queries with j in that pass via
//     float4 dots against coalesced alphaT rows.
__global__ __launch_bounds__(1024, 1) void hawkes_kernel(
        const int* __restrict__ tq, const int* __restrict__ sq,
        const int* __restrict__ obs,      // [T][S] int32
        const float* __restrict__ beta, const float* __restrict__ mu,
        const float* __restrict__ alphaT, // ws, [s][sp]
        float* __restrict__ out) {
    const int k    = blockIdx.x;
    const int tid  = threadIdx.x;
    const int wv   = tid >> 6, lane = tid & 63;
    const float b  = beta[0];
    const float a  = expf(-b);
    const int  t0  = k << 5;

    __shared__ int   qtmp[QCAP];                 // (j<<13)|i
    __shared__ int   qcnt_s;
    __shared__ float Gall[PASS_ROWS][S_DIM];     // 32 KB; rows 0..3 double as comb

    if (tid == 0) qcnt_s = 0;
    __syncthreads();

    // ---- 1) bucket queries ----
    for (int i = tid; i < B_DIM; i += 1024) {
        int tv = tq[i];
        if ((tv >> 5) == k) {
            int p = atomicAdd(&qcnt_s, 1);
            if (p < QCAP) qtmp[p] = ((tv - t0) << 13) | i;
        }
    }

    // ---- 2) truncated prefix ----
    int Dmax = ((int)(26.0f / b) + 4 + 3) & ~3;  // beta*n >= 26, mult of 4
    const int n  = t0 < Dmax ? t0 : Dmax;        // t0 % 32 == 0 -> n % 4 == 0
    const int ts = t0 - n;
    const int Q4 = n >> 2;

    const int m  = tid >> 8;                     // phase 0..3
    const int c4 = (tid & 255) << 2;             // 4-column group
    float A4 = a * a; A4 = A4 * A4;              // a^4
    float F0 = 0.f, F1 = 0.f, F2 = 0.f, F3 = 0.f;
    const int* obase = obs + (size_t)(ts + m) * S_DIM + c4;

    int q = 0;
    for (; q + 8 <= Q4; q += 8) {
        int4 o[8];
        #pragma unroll
        for (int r = 0; r < 8; ++r)
            o[r] = *(const int4*)(obase + (size_t)(q + r) * 4 * S_DIM);
        #pragma unroll
        for (int r = 0; r < 8; ++r) {
            F0 = A4 * (F0 + (float)o[r].x);
            F1 = A4 * (F1 + (float)o[r].y);
            F2 = A4 * (F2 + (float)o[r].z);
            F3 = A4 * (F3 + (float)o[r].w);
        }
    }
    for (; q < Q4; ++q) {
        int4 ov = *(const int4*)(obase + (size_t)q * 4 * S_DIM);
        F0 = A4 * (F0 + (float)ov.x);
        F1 = A4 * (F1 + (float)ov.y);
        F2 = A4 * (F2 + (float)ov.z);
        F3 = A4 * (F3 + (float)ov.w);
    }
    // phase weight a^{-m} (bounded by e^3)
    float inva = 1.f / a;
    float am = (m == 0) ? 1.f : (m == 1) ? inva
             : (m == 2) ? inva * inva : inva * inva * inva;
    float4 cw; cw.x = F0 * am; cw.y = F1 * am; cw.z = F2 * am; cw.w = F3 * am;
    __syncthreads();                     // also covers bucket-write completion
    *(float4*)&Gall[m][c4] = cw;         // comb[m][c4..c4+3]
    __syncthreads();
    float U = Gall[0][tid] + Gall[1][tid] + Gall[2][tid] + Gall[3][tid];
    __syncthreads();                     // comb consumed before pass 0 reuse
    const int Q = qcnt_s < QCAP ? qcnt_s : QCAP;

    // ---- 3) roll + answer ----
    float G = U;                         // G == G_{t0}
    for (int pass = 0; pass < NPASS; ++pass) {
        const int jlo = pass * PASS_ROWS;
        int o[PASS_ROWS];
        #pragma unroll
        for (int r = 0; r < PASS_ROWS; ++r)
            o[r] = obs[(size_t)(t0 + jlo + r) * S_DIM + tid];
        #pragma unroll
        for (int r = 0; r < PASS_ROWS; ++r) {
            Gall[r][tid] = G;            // G_{t0+jlo+r}
            G = a * (G + (float)o[r]);   // absorb row -> G_{t0+jlo+r+1}
        }
        __syncthreads();                 // Gall visible
        for (int p = wv; p < Q; p += 16) {
            int key = qtmp[p];           // wave-uniform broadcast
            int j = key >> 13;
            if (j < jlo || j >= jlo + PASS_ROWS) continue;
            int i = key & 8191;
            int s = sq[i];
            const float* ar = alphaT + (size_t)s * S_DIM;
            const float* gr = &Gall[j - jlo][0];
            float acc = 0.f;
            #pragma unroll
            for (int cc = 0; cc < 4; ++cc) {
                float4 gv = *(const float4*)(gr + 256 * cc + lane * 4);
                float4 av = *(const float4*)(ar + 256 * cc + lane * 4);
                acc += gv.x * av.x + gv.y * av.y + gv.z * av.z + gv.w * av.w;
            }
            #pragma unroll
            for (int off = 32; off > 0; off >>= 1)
                acc += __shfl_down(acc, off);
            if (lane == 0) {
                float lam = mu[s] + b * acc;
                out[i] = lam > 0.f ? lam : 0.f;
            }
        }
        __syncthreads();                 // queries done before Gall reuse
    }
}

// ---------------------------------------------------------------------------
// Fallback: proven R5 single-kernel zero-ws version (874 us, absmax 0.0).
__global__ __launch_bounds__(1024) void chunk_all_kernel(
        const int* __restrict__ tq, const int* __restrict__ sq,
        const int* __restrict__ obs, const float* __restrict__ alpha,
        const float* __restrict__ beta, const float* __restrict__ mu,
        float* __restrict__ out) {
    const int k   = blockIdx.x;
    const int tid = threadIdx.x;
    const float b = beta[0];
    const float a = expf(-b);
    const int t0 = k << 6;
    __shared__ int   qkey[2048];
    __shared__ int   qcnt_s;
    __shared__ float wred[16];
    if (tid == 0) qcnt_s = 0;
    __syncthreads();
    for (int i = tid; i < B_DIM; i += 1024) {
        int tv = tq[i];
        if ((tv >> 6) == k) {
            int p = atomicAdd(&qcnt_s, 1);
            if (p < 2048) qkey[p] = ((tv - t0) << 13) | i;
        }
    }
    __syncthreads();
    int Q = qcnt_s; if (Q > 2048) Q = 2048;
    float G = 0.f;
    for (int tp = 0; tp < t0; tp += 8) {
        int o[8];
        #pragma unroll
        for (int r = 0; r < 8; ++r) o[r] = obs[(size_t)(tp + r) * S_DIM + tid];
        #pragma unroll
        for (int r = 0; r < 8; ++r) G = a * (G + (float)o[r]);
    }
    for (int j = 0; j < 64; ++j) {
        for (int q = 0; q < Q; ++q) {
            int key = qkey[q];
            if ((key >> 13) == j) {
                int i = key & 8191;
                int s = sq[i];
                float p = G * alpha[(size_t)tid * S_DIM + s];
                #pragma unroll
                for (int off = 32; off > 0; off >>= 1) p += __shfl_down(p, off);
                if ((tid & 63) == 0) wred[tid >> 6] = p;
                __syncthreads();
                if (tid < 64) {
                    float v = (tid < 16) ? wred[tid] : 0.f;
                    v += __shfl_down(v, 8); v += __shfl_down(v, 4);
                    v += __shfl_down(v, 2); v += __shfl_down(v, 1);
                    if (tid == 0) {
                        float lam = mu[s] + b * v;
                        out[i] = lam > 0.f ? lam : 0.f;
                    }
                }
                __syncthreads();
            }
        }
        int o = obs[(size_t)(t0 + j) * S_DIM + tid];
        G = a * (G + (float)o);
    }
}

// ---------------------------------------------------------------------------
extern "C" void kernel_launch(void* const* d_in, const int* in_sizes, int n_in,
                              void* d_out, int out_size, void* d_ws, size_t ws_size,
                              hipStream_t stream) {
    const int*   t     = (const int*)d_in[0];
    const int*   s     = (const int*)d_in[1];
    const int*   obs   = (const int*)d_in[2];
    const float* alpha = (const float*)d_in[3];
    const float* beta  = (const float*)d_in[4];
    const float* mu    = (const float*)d_in[5];
    float* out = (float*)d_out;

    if (ws_size < (size_t)WS_NEEDED || d_ws == nullptr) {
        chunk_all_kernel<<<128, 1024, 0, stream>>>(t, s, obs, alpha, beta, mu, out);
        return;
    }

    float* alphaT = (float*)d_ws;
    transpose_alpha_kernel<<<dim3(32, 32), dim3(32, 8), 0, stream>>>(alpha, alphaT);
    hawkes_kernel<<<NCHUNK, 1024, 0, stream>>>(t, s, obs, beta, mu, alphaT, out);
}